// Round 12
// baseline (87.213 us; speedup 1.0000x reference)
//
#include <hip/hip_runtime.h>
#include <math.h>

#define TOKENS 16384
#define DIM 4096
#define NE 64
#define BM 32
#define NKT4 16                            // 256-wide K tiles
#define NBLK 512

// ws float offsets
#define WS_META  256                       // float4 per token: 65536 floats
#define WS_PART  65792                     // 512 blocks x 192 floats
#define WS_WST   164096                    // 524288 ushorts = W f16 2-plane frag-linear

typedef __attribute__((ext_vector_type(8))) _Float16 f16x8;
typedef __attribute__((ext_vector_type(16))) float f32x16;

// W [4096][64] f32 -> wst: per 64k unit u (64 units), 16 fragments of 1 KB.
//   offset = u*8192 + step*2048 + p*1024 + eh*512 + lane*8
//   value = plane-p f16 of 4096*W[u*64 + step*16 + (lane>>5)*8 + j][eh*32 + (lane&31)]
__global__ __launch_bounds__(64) void wconv(const float* __restrict__ W,
                                            ushort* __restrict__ wst) {
    const int b = blockIdx.x;
    const int u = b >> 2, s = b & 3;
    const int lane = threadIdx.x;
    const int l31 = lane & 31, khf = lane >> 5;
    #pragma unroll
    for (int eh = 0; eh < 2; eh++) {
        int e = eh * 32 + l31;
        f16x8 H, M;
        #pragma unroll
        for (int j = 0; j < 8; j++) {
            float f = 4096.0f * W[(size_t)(u * 64 + s * 16 + khf * 8 + j) * NE + e];
            _Float16 hh = (_Float16)f;
            H[j] = hh;
            M[j] = (_Float16)(f - (float)hh);
        }
        size_t o = (size_t)u * 8192 + (size_t)s * 2048 + (size_t)eh * 512
                 + (size_t)lane * 8;
        *(f16x8*)(wst + o)        = H;     // p = 0
        *(f16x8*)(wst + o + 1024) = M;     // p = 1
    }
}

// LDS x buffer (32 KB each, 2 deep), BK=256:
//   byte(r, cs) = r*1024 + cs*16 ; stored chunk cs holds logical chunk
//   c = (cs & 56) | ((cs & 7) ^ (r & 7))   (16B chunks, 64 per row)
__global__ __launch_bounds__(256, 2) void gate_main(const float* __restrict__ x,
        const ushort* __restrict__ wst, const float* __restrict__ bias,
        float* __restrict__ ws) {

    __shared__ __align__(16) char smem[2][32768];
    __shared__ float tmax[BM], tinv[BM];
    __shared__ float pp[4][NE];
    __shared__ float sg0[BM], sg1[BM];
    __shared__ int   si0[BM], si1[BM];

    const int tid = threadIdx.x, wave = tid >> 6, lane = tid & 63;
    const int l31 = lane & 31, khf = lane >> 5;
    const int s = wave;                // 64-k unit owner within each tile
    const int tb = blockIdx.x * BM;
    const int blk = blockIdx.x;

    f32x16 acc0, acc1;                 // expert halves
    #pragma unroll
    for (int i = 0; i < 16; i++) { acc0[i] = 0.0f; acc1[i] = 0.0f; }

    // x staging: op q stages ROW (wave*8+q), one 1 KB contiguous burst.
    auto issue_x = [&](char* B, int kt) {
        #pragma unroll
        for (int q = 0; q < 8; q++) {
            int r = wave * 8 + q;
            int c = (lane & 56) | ((lane & 7) ^ (r & 7));   // inverse swizzle on src
            const float* src = x + (size_t)(tb + r) * DIM + kt * 256 + c * 4;
            __builtin_amdgcn_global_load_lds(
                (const __attribute__((address_space(1))) uint*)src,
                (__attribute__((address_space(3))) uint*)
                    (B + r * 1024 + lane * 16), 16, 0, 0);
        }
    };

    const uint rbase = (uint)l31 * 1024;
    const uint rx = (uint)(l31 & 7);

    auto split8 = [&](float4 A0, float4 A1, f16x8& ah, f16x8& am) {
        float f[8] = {A0.x, A0.y, A0.z, A0.w, A1.x, A1.y, A1.z, A1.w};
        #pragma unroll
        for (int j = 0; j < 8; j++) {
            float v = 512.0f * f[j];
            _Float16 hh = (_Float16)v;
            ah[j] = hh;
            am[j] = (_Float16)(v - (float)hh);
        }
    };

    auto body = [&](int kt, bool pf) {
        const char* B = smem[kt & 1];
        // ---- W fragments (this wave's 64-k unit): L2 -> regs, pinned first
        const ushort* wk = wst + (size_t)(4 * kt + s) * 8192 + (size_t)lane * 8;
        f16x8 w0[4], w1[4], w2[4], w3[4];
        #pragma unroll
        for (int si = 0; si < 4; si++) {
            const ushort* p = wk + si * 2048;
            w0[si] = *(const f16x8*)(p);          // p0 eh0
            w1[si] = *(const f16x8*)(p + 512);    // p0 eh1
            w2[si] = *(const f16x8*)(p + 1024);   // p1 eh0
            w3[si] = *(const f16x8*)(p + 1536);   // p1 eh1
        }
        __builtin_amdgcn_sched_barrier(0);        // W issued before x prefetch
        if (pf) issue_x(smem[(kt + 1) & 1], kt + 1);
        // ---- 4 x 16-k steps
        #pragma unroll
        for (int si = 0; si < 4; si++) {
            uint c0 = (uint)(s * 16 + si * 4 + khf * 2);
            uint cs0 = (c0 & 56u) | ((c0 & 7u) ^ rx);
            float4 A0 = *(const float4*)(B + rbase + cs0 * 16);
            float4 A1 = *(const float4*)(B + rbase + (cs0 ^ 1u) * 16);
            f16x8 ah, am;
            split8(A0, A1, ah, am);
            __builtin_amdgcn_s_setprio(1);
            acc0 = __builtin_amdgcn_mfma_f32_32x32x16_f16(ah, w0[si], acc0, 0, 0, 0);
            acc1 = __builtin_amdgcn_mfma_f32_32x32x16_f16(ah, w1[si], acc1, 0, 0, 0);
            acc0 = __builtin_amdgcn_mfma_f32_32x32x16_f16(am, w0[si], acc0, 0, 0, 0);
            acc1 = __builtin_amdgcn_mfma_f32_32x32x16_f16(am, w1[si], acc1, 0, 0, 0);
            acc0 = __builtin_amdgcn_mfma_f32_32x32x16_f16(ah, w2[si], acc0, 0, 0, 0);
            acc1 = __builtin_amdgcn_mfma_f32_32x32x16_f16(ah, w3[si], acc1, 0, 0, 0);
            __builtin_amdgcn_s_setprio(0);
        }
    };

    issue_x(smem[0], 0);
    for (int kt = 0; kt < NKT4; kt++) {
        asm volatile("s_waitcnt vmcnt(0)" ::: "memory");
        __builtin_amdgcn_s_barrier();
        body(kt, kt + 1 < NKT4);
    }
    __syncthreads();

    // epilogue: sequential cross-wave K reduction into lgf (aliases smem)
    // C/D: col = eh*32 + (lane&31), row = (reg&3) + 8*(reg>>2) + 4*khf
    float* lgf = (float*)smem;         // lg[32][68] = 8704 B
    const float scale = 1.0f / 2097152.0f;   // 2^-21 = 1/(512*4096)
    for (int p = 0; p < 4; p++) {
        if (s == p) {
            float b0 = bias[l31], b1 = bias[32 + l31];
            #pragma unroll
            for (int r = 0; r < 16; r++) {
                int row = (r & 3) + 8 * (r >> 2) + 4 * khf;
                if (p == 0) {
                    lgf[row * 68 + l31]      = acc0[r] * scale + b0;
                    lgf[row * 68 + 32 + l31] = acc1[r] * scale + b1;
                } else {
                    lgf[row * 68 + l31]      += acc0[r] * scale;
                    lgf[row * 68 + 32 + l31] += acc1[r] * scale;
                }
            }
        }
        __syncthreads();
    }

    // per-token softmax + top-2 (threads 0..31) — no atomics
    if (tid < BM) {
        const int t = tid;
        float m = -INFINITY;
        #pragma unroll
        for (int e = 0; e < NE; e++) m = fmaxf(m, lgf[t * 68 + e]);
        float sum = 0.0f;
        float v0 = -INFINITY, v1 = -INFINITY;
        int i0 = 0, i1 = 1;
        #pragma unroll
        for (int e = 0; e < NE; e++) {
            float l = lgf[t * 68 + e];
            sum += expf(l - m);
            if (l > v0) { v1 = v0; i1 = i0; v0 = l; i0 = e; }
            else if (l > v1) { v1 = l; i1 = e; }
        }
        float inv = 1.0f / sum;
        tmax[t] = m; tinv[t] = inv;
        float g0 = expf(v0 - m) * inv;
        float g1 = expf(v1 - m) * inv;
        sg0[t] = g0; sg1[t] = g1; si0[t] = i0; si1[t] = i1;
        float4 mt4;
        mt4.x = __int_as_float(i0);
        mt4.y = __int_as_float(i1);
        mt4.z = g0; mt4.w = g1;
        ((float4*)(ws + WS_META))[tb + t] = mt4;
    }
    __syncthreads();

    // per-expert gate-score partial sums (density_proxy numerator)
    {
        int e = tid & 63;
        int grp = tid >> 6;    // 0..3, 8 tokens each
        float p = 0.0f;
        #pragma unroll
        for (int r = 0; r < 8; r++) {
            int t = grp * 8 + r;
            p += expf(lgf[t * 68 + e] - tmax[t]) * tinv[t];
        }
        pp[grp][e] = p;
    }
    __syncthreads();

    // deterministic per-block partials: [blk][0:64)=denom, [64:128)=proxy, [128:192)=count
    if (tid < NE) {
        int e = tid;
        float d = 0.0f, c = 0.0f;
        #pragma unroll
        for (int t = 0; t < BM; t++) {
            if (si0[t] == e) { d += sg0[t]; c += 1.0f; }
            if (si1[t] == e) { d += sg1[t]; c += 1.0f; }
        }
        float pr = pp[0][e] + pp[1][e] + pp[2][e] + pp[3][e];
        float* P = ws + WS_PART + (size_t)blk * 192;
        P[e]       = d;
        P[64 + e]  = pr;
        P[128 + e] = c;
    }
}

// finals: ws[0:64)=denom, ws[64:128)=proxy, ws[128:192)=count
__global__ __launch_bounds__(64) void gate_reduce(const float* __restrict__ part,
                                                  float* __restrict__ ws) {
    const int f = blockIdx.x;      // 0..191
    const int lane = threadIdx.x;  // 0..63
    float s = 0.0f;
    #pragma unroll
    for (int j = 0; j < 8; j++)
        s += part[(size_t)(lane * 8 + j) * 192 + f];
    #pragma unroll
    for (int off = 32; off; off >>= 1) s += __shfl_down(s, off);
    if (lane == 0) ws[f] = s;
}

__global__ __launch_bounds__(256) void gate_write(const float* __restrict__ ws,
                                                  float* __restrict__ out) {
    const float CAP = 16384.0f;
    int tid = threadIdx.x;
    int tl = tid >> 4;
    int e4 = (tid & 15) * 4;
    int t = blockIdx.x * 16 + tl;
    float4 mt = ((const float4*)(ws + WS_META))[t];
    int i0 = __float_as_int(mt.x), i1 = __float_as_int(mt.y);
    float s0 = mt.z * CAP / (ws[i0] + 1e-6f);
    float s1 = mt.w * CAP / (ws[i1] + 1e-6f);
    float4 v = {0.0f, 0.0f, 0.0f, 0.0f};
    float* vp = (float*)&v;
    #pragma unroll
    for (int j = 0; j < 4; j++) {
        int e = e4 + j;
        vp[j] = (e == i0) ? s0 : ((e == i1) ? s1 : 0.0f);
    }
    *(float4*)(out + (size_t)t * NE + e4) = v;
    // loss folded in: block 0, first wave
    if (blockIdx.x == 0 && tid < 64) {
        float lv = ws[64 + tid] * ws[128 + tid];
        #pragma unroll
        for (int off = 32; off; off >>= 1) lv += __shfl_down(lv, off);
        if (tid == 0)
            out[(size_t)TOKENS * NE] = 64.0f * lv / (16384.0f * 16384.0f);
    }
}

extern "C" void kernel_launch(void* const* d_in, const int* in_sizes, int n_in,
                              void* d_out, int out_size, void* d_ws, size_t ws_size,
                              hipStream_t stream) {
    const float* x = (const float*)d_in[0];
    const float* W = (const float*)d_in[1];
    const float* b = (const float*)d_in[2];
    float* out = (float*)d_out;
    float* ws = (float*)d_ws;
    ushort* wst = (ushort*)(ws + WS_WST);

    hipLaunchKernelGGL(wconv, dim3(256), dim3(64), 0, stream, W, wst);
    hipLaunchKernelGGL(gate_main, dim3(NBLK), dim3(256), 0, stream, x, wst, b, ws);
    hipLaunchKernelGGL(gate_reduce, dim3(192), dim3(64), 0, stream,
                       ws + WS_PART, ws);
    hipLaunchKernelGGL(gate_write, dim3(TOKENS / 16), dim3(256), 0, stream, ws, out);
}